// Round 1
// 719.146 us; speedup vs baseline: 1.0231x; 1.0231x over previous
//
#include <hip/hip_runtime.h>

#define N_  4096
#define C_  256
#define HI_ 64
#define HO_ 128

typedef __attribute__((ext_vector_type(8))) short bf16x8;
typedef __attribute__((ext_vector_type(4))) short bf16x4;
typedef __attribute__((ext_vector_type(4))) float f32x4;

// fp32 -> bf16 round-to-nearest-even
__device__ __forceinline__ short f2bf(float f) {
    union { float f; unsigned u; } v; v.f = f;
    unsigned r = v.u + 0x7fffu + ((v.u >> 16) & 1u);
    return (short)(r >> 16);
}

// Block = 256 threads (4 waves): one channel c, 256 consecutive n-rows.
// All global traffic is lane-contiguous; MFMA fragment scatter is done in LDS.
// LDS bf16 rows are 128B; 16B-slot s of row R lives at slot (s ^ (R&7)) (bank-balanced).
__global__ __launch_bounds__(256) void dw_v2(
    const float* __restrict__ x, const float* __restrict__ W,
    const float* __restrict__ bias, float* __restrict__ out)
{
    __shared__ __align__(16) short wbuf[128 * 64];      // W_c bf16, swizzled      (16 KB)
    __shared__ __align__(16) short xbuf[4][16 * 64];    // per-wave x tile, swz    ( 8 KB)
    __shared__ __align__(16) float ebuf[4][8 * 132];    // per-wave epilogue, pad  (16.5 KB)

    const int bx   = blockIdx.x;
    const int c    = bx & (C_ - 1);
    const int nseg = bx >> 8;
    const int tid  = threadIdx.x;
    const int wave = tid >> 6;
    const int lane = tid & 63;
    const int lr   = lane & 15;      // A-row (n) / B-col (o) within tile
    const int kq   = lane >> 4;      // k-quad

    // ---- Stage W_c -> LDS bf16 (block-wide, fully coalesced: 8 x float4/thread) ----
    {
        const float* Wc = W + c * (HO_ * HI_);
        #pragma unroll
        for (int j = 0; j < 8; ++j) {
            const int row = j * 16 + (tid >> 4);      // o-row 0..127
            const int f   = tid & 15;                 // float4 index in 256B row
            const float4 w = *reinterpret_cast<const float4*>(Wc + row * HI_ + f * 4);
            bf16x4 v; v[0]=f2bf(w.x); v[1]=f2bf(w.y); v[2]=f2bf(w.z); v[3]=f2bf(w.w);
            const int slot = f >> 1, low = f & 1;
            *reinterpret_cast<bf16x4*>(
                &wbuf[row * 64 + (((slot ^ (row & 7)) << 3) + low * 4)]) = v;
        }
    }
    // bias for this lane's (fixed) output columns (i&31)*4 .. +3
    const float4 bv4 = *reinterpret_cast<const float4*>(bias + c * HO_ + (lane & 31) * 4);
    __syncthreads();   // only barrier: wbuf shared across waves

    short* xb = xbuf[wave];
    float* eb = ebuf[wave];
    const int  n_wave  = nseg * 256 + wave * 64;
    const long xrow    = (long)C_ * HI_;                  // row stride in floats
    const float* xbase = x + ((long)n_wave * C_ + c) * HI_;

    // prefetch chunk 0: 16 lanes cover one full 256B row -> coalesced
    float4 pf[4];
    #pragma unroll
    for (int j = 0; j < 4; ++j) {
        const int R = j * 4 + (lane >> 4);
        pf[j] = *reinterpret_cast<const float4*>(xbase + (long)R * xrow + (lane & 15) * 4);
    }

    #pragma unroll
    for (int ch = 0; ch < 4; ++ch) {
        // ---- stage current chunk into LDS (bf16, swizzled) ----
        #pragma unroll
        for (int j = 0; j < 4; ++j) {
            const int R = j * 4 + (lane >> 4);
            bf16x4 v; v[0]=f2bf(pf[j].x); v[1]=f2bf(pf[j].y); v[2]=f2bf(pf[j].z); v[3]=f2bf(pf[j].w);
            const int f = lane & 15, slot = f >> 1, low = f & 1;
            *reinterpret_cast<bf16x4*>(
                &xb[R * 64 + (((slot ^ (R & 7)) << 3) + low * 4)]) = v;
        }
        // ---- prefetch next chunk (hides HBM latency under MFMA+epilogue) ----
        if (ch < 3) {
            #pragma unroll
            for (int j = 0; j < 4; ++j) {
                const int R = (ch + 1) * 16 + j * 4 + (lane >> 4);
                pf[j] = *reinterpret_cast<const float4*>(xbase + (long)R * xrow + (lane & 15) * 4);
            }
        }
        // ---- A fragments from LDS: k = kq*8 + kb*32 + j ----
        bf16x8 afrag[2];
        #pragma unroll
        for (int kb = 0; kb < 2; ++kb)
            afrag[kb] = *reinterpret_cast<bf16x8*>(
                &xb[lr * 64 + (((kq + 4 * kb) ^ (lr & 7)) << 3)]);

        // ---- MFMA: 8 o-tiles x 2 k-steps, B-frags streamed from LDS ----
        f32x4 acc[8];
        #pragma unroll
        for (int ot = 0; ot < 8; ++ot) acc[ot] = (f32x4){0.f, 0.f, 0.f, 0.f};
        #pragma unroll
        for (int kb = 0; kb < 2; ++kb) {
            #pragma unroll
            for (int ot = 0; ot < 8; ++ot) {
                const int o = ot * 16 + lr;
                const bf16x8 bfrag = *reinterpret_cast<bf16x8*>(
                    &wbuf[o * 64 + (((kq + 4 * kb) ^ (o & 7)) << 3)]);
                acc[ot] = __builtin_amdgcn_mfma_f32_16x16x32_bf16(
                    afrag[kb], bfrag, acc[ot], 0, 0, 0);
            }
        }

        // ---- Epilogue: transpose acc through LDS -> float4 coalesced stores ----
        // acc layout: lane (lr,kq), reg (ot,r) -> D[row=kq*4+r][col=lr+16*ot]
        // two halves (r=0,1 then r=2,3) to halve the LDS footprint
        const int n1 = n_wave + ch * 16;
        #pragma unroll
        for (int h = 0; h < 2; ++h) {
            #pragma unroll
            for (int rr = 0; rr < 2; ++rr) {
                const int r    = h * 2 + rr;
                const int slot = kq * 2 + rr;            // buffer slot for row kq*4+h*2+rr
                #pragma unroll
                for (int ot = 0; ot < 8; ++ot)
                    eb[slot * 132 + ot * 16 + lr] = acc[ot][r];
            }
            #pragma unroll
            for (int j = 0; j < 4; ++j) {
                const int slot = 2 * j + (lane >> 5);
                const int row  = (slot >> 1) * 4 + h * 2 + (slot & 1);
                float4 v = *reinterpret_cast<float4*>(&eb[slot * 132 + (lane & 31) * 4]);
                v.x += bv4.x; v.y += bv4.y; v.z += bv4.z; v.w += bv4.w;
                // 2 rows x 512B fully contiguous per store instruction
                *reinterpret_cast<float4*>(
                    out + ((long)(n1 + row) * C_ + c) * HO_ + (lane & 31) * 4) = v;
            }
        }
    }
}

extern "C" void kernel_launch(void* const* d_in, const int* in_sizes, int n_in,
                              void* d_out, int out_size, void* d_ws, size_t ws_size,
                              hipStream_t stream) {
    const float* x  = (const float*)d_in[0];
    const float* W  = (const float*)d_in[1];
    const float* b  = (const float*)d_in[2];
    float* out      = (float*)d_out;
    const int blocks = C_ * (N_ / 256);   // 4096
    dw_v2<<<dim3(blocks), dim3(256), 0, stream>>>(x, W, b, out);
}